// Round 8
// baseline (576.914 us; speedup 1.0000x reference)
//
#include <hip/hip_runtime.h>
#include <cmath>

namespace {

typedef float f32x4 __attribute__((ext_vector_type(4)));

constexpr int Bb   = 128;
constexpr int Nn   = 32;
constexpr int Tt   = 50;
constexpr int Hh   = 128;
constexpr int HOPS = 8;
constexpr int NT   = Nn * Tt;                  // 1600
constexpr int PPT  = 5;                        // positions per thread (passes)
constexpr int POS_PER_BLOCK = 16 * PPT;        // 80
constexpr int CHUNKS = NT / POS_PER_BLOCK;     // 20 blocks per b

// Fused kernel: per-block s1 compute + neigh_r copy (R5 structure, 2560 blocks),
// then the LAST block of each b (device-scope counter) performs softmax + BW.
// Journal: nt-loads lose L3 residency (R2, +17us); nt-stores defeat L2 write
// combining, WRITE_SIZE 109->158MB (R6, +10us); CPB=2 block-merge drops
// occupancy/L2 locality (R7, +3.4us). Temporal + 2560 blocks is the optimum.
__global__ __launch_bounds__(256) void ga_fused(
    const float* __restrict__ node,     // [B][T][H]
    const float* __restrict__ neigh,    // [B][NT][H]
    const int*   __restrict__ nn,       // [B]
    const float* __restrict__ W,        // [HOPS][H]
    const float* __restrict__ bias,     // [HOPS]
    float* __restrict__ out,            // BW | BA | neigh_r
    unsigned int* __restrict__ counters)// [B], zeroed per call
{
    const int lane16 = threadIdx.x & 15;   // h-slice owner within a 16-lane group
    const int group  = threadIdx.x >> 4;   // 16 position-groups per block
    const int chunk  = blockIdx.x % CHUNKS;
    const int b      = blockIdx.x / CHUNKS;

    float* BW      = out;                                  // [B][NT]
    float* BA      = out + (size_t)Bb * NT;                // [B][HOPS][NT]
    float* neigh_r = BA + (size_t)Bb * HOPS * NT;          // [B][NT][H]

    const float rscale = rsqrtf((float)nn[0]);

    // W fragment for this thread's fixed h-slice (h = lane16*8 .. +7)
    f32x4 w0[HOPS], w1[HOPS];
    #pragma unroll
    for (int a = 0; a < HOPS; ++a) {
        const f32x4* wp = reinterpret_cast<const f32x4*>(W + a * Hh + lane16 * 8);
        w0[a] = wp[0];
        w1[a] = wp[1];
    }
    const float bl = bias[lane16 >> 1];   // hop owned by this lane-pair after butterfly

    const int pos0 = chunk * POS_PER_BLOCK + group;       // pass p handles pos0 + 16p
    const size_t base = ((size_t)b * NT + pos0) * Hh + lane16 * 8;

    // 1) hoist all passes' neigh loads: 2*PPT dwordx4 in flight
    f32x4 nb[PPT][2];
    #pragma unroll
    for (int p = 0; p < PPT; ++p) {
        const f32x4* np = reinterpret_cast<const f32x4*>(neigh + base + (size_t)p * 16 * Hh);
        nb[p][0] = np[0];
        nb[p][1] = np[1];
    }
    // 2) fused passthrough copy (exact f32)
    #pragma unroll
    for (int p = 0; p < PPT; ++p) {
        f32x4* cp = reinterpret_cast<f32x4*>(neigh_r + base + (size_t)p * 16 * Hh);
        cp[0] = nb[p][0];
        cp[1] = nb[p][1];
    }

    // 3) compute + payload-split butterfly reduce (8 shuffles per pass)
    #pragma unroll
    for (int p = 0; p < PPT; ++p) {
        const int pos = pos0 + p * 16;
        const int t   = pos % Tt;
        const f32x4* dp = reinterpret_cast<const f32x4*>(node + ((size_t)b * Tt + t) * Hh + lane16 * 8);
        const f32x4 pr0 = nb[p][0] * dp[0];
        const f32x4 pr1 = nb[p][1] * dp[1];

        float acc[HOPS];
        #pragma unroll
        for (int a = 0; a < HOPS; ++a) {
            acc[a] = pr0[0] * w0[a][0] + pr0[1] * w0[a][1] + pr0[2] * w0[a][2] + pr0[3] * w0[a][3]
                   + pr1[0] * w1[a][0] + pr1[1] * w1[a][1] + pr1[2] * w1[a][2] + pr1[3] * w1[a][3];
        }

        // Level 1 (xor 8): keep own half of hop-set, exchange the other half.
        const bool h8 = (lane16 & 8) != 0;
        float r[4];
        #pragma unroll
        for (int k = 0; k < 4; ++k) {
            float send = h8 ? acc[k] : acc[k + 4];
            r[k] = (h8 ? acc[k + 4] : acc[k]) + __shfl_xor(send, 8, 64);
        }
        // Level 2 (xor 4)
        const bool h4 = (lane16 & 4) != 0;
        float s2[2];
        #pragma unroll
        for (int k = 0; k < 2; ++k) {
            float send = h4 ? r[k] : r[k + 2];
            s2[k] = (h4 ? r[k + 2] : r[k]) + __shfl_xor(send, 4, 64);
        }
        // Level 3 (xor 2)
        const bool h2 = (lane16 & 2) != 0;
        float send3 = h2 ? s2[0] : s2[1];
        float u = (h2 ? s2[1] : s2[0]) + __shfl_xor(send3, 2, 64);
        // Level 4 (xor 1): full sum; lane 2k (and 2k+1) now hold hop k's total
        u += __shfl_xor(u, 1, 64);

        if (!(lane16 & 1)) {
            const int k = lane16 >> 1;
            BA[((size_t)b * HOPS + k) * NT + pos] = (u + bl) * rscale;
        }
    }

    // ---- last-block-per-b: softmax + BW (threadFenceReduction pattern) ----
    __threadfence();                       // release: s1 stores visible device-wide
    __shared__ unsigned int old_s;
    if (threadIdx.x == 0) old_s = atomicAdd(&counters[b], 1u);
    __syncthreads();
    if (old_s != CHUNKS - 1) return;       // uniform across block
    __threadfence();                       // acquire: see all 20 blocks' s1 writes

    const int wv = threadIdx.x >> 6;       // wave 0..3 -> hop rows {2wv, 2wv+1}
    const int ln = threadIdx.x & 63;

    __shared__ float sBW[NT];              // 6.4 KB: BW accumulator
    for (int nt = threadIdx.x; nt < NT; nt += 256) sBW[nt] = 0.f;
    __syncthreads();

    #pragma unroll
    for (int rr = 0; rr < 2; ++rr) {
        const int r = wv * 2 + rr;
        float* row = BA + ((size_t)b * HOPS + r) * NT;

        float m = -INFINITY;
        #pragma unroll
        for (int k = 0; k < 25; ++k) m = fmaxf(m, row[ln + 64 * k]);
        #pragma unroll
        for (int off = 32; off >= 1; off >>= 1) m = fmaxf(m, __shfl_xor(m, off, 64));

        float ssum = 0.f;
        float e[25];
        #pragma unroll
        for (int k = 0; k < 25; ++k) {
            e[k] = __expf(row[ln + 64 * k] - m);
            ssum += e[k];
        }
        #pragma unroll
        for (int off = 32; off >= 1; off >>= 1) ssum += __shfl_xor(ssum, off, 64);
        const float inv = 1.0f / ssum;

        #pragma unroll
        for (int k = 0; k < 25; ++k) {
            const int nt = ln + 64 * k;
            const float p = e[k] * inv;
            row[nt] = p;
            atomicAdd(&sBW[nt], p);        // ds_add_f32, cross-wave safe
        }
    }
    __syncthreads();
    for (int nt = threadIdx.x; nt < NT; nt += 256)
        BW[(size_t)b * NT + nt] = sBW[nt];
}

} // namespace

extern "C" void kernel_launch(void* const* d_in, const int* in_sizes, int n_in,
                              void* d_out, int out_size, void* d_ws, size_t ws_size,
                              hipStream_t stream) {
    const float* node  = (const float*)d_in[0];   // [128][50][128] f32
    const float* neigh = (const float*)d_in[1];   // [128][32][50][128] f32
    const int*   nn    = (const int*)d_in[2];     // [128] i32
    const float* W     = (const float*)d_in[3];   // [8][128] f32
    const float* bias  = (const float*)d_in[4];   // [8] f32

    unsigned int* counters = (unsigned int*)d_ws;
    hipMemsetAsync(counters, 0, Bb * sizeof(unsigned int), stream);

    ga_fused<<<dim3(Bb * CHUNKS), dim3(256), 0, stream>>>(
        node, neigh, nn, W, bias, (float*)d_out, counters);
}

// Round 9
// 50.751 us; speedup vs baseline: 11.3674x; 11.3674x over previous
//
#include <hip/hip_runtime.h>
#include <cmath>

namespace {

typedef float f32x4 __attribute__((ext_vector_type(4)));

constexpr int Bb   = 128;
constexpr int Nn   = 32;
constexpr int Tt   = 50;
constexpr int Hh   = 128;
constexpr int HOPS = 8;
constexpr int NT   = Nn * Tt;                  // 1600
constexpr int PPT  = 5;                        // positions per thread (passes)
constexpr int POS_PER_BLOCK = 16 * PPT;        // 80
constexpr int CHUNKS = NT / POS_PER_BLOCK;     // 20

// ===== Failure ledger (keep; each was bench-falsified) =====
// R2: __builtin_nontemporal_load on neigh  -> +17us (loses L3 residency across replays)
// R6: __builtin_nontemporal_store neigh_r  -> +10us (defeats L2 write-combining; WRITE 109->158MB)
// R7: 2 chunks/block                       -> +3.4us (VGPR 64->68 crosses 32->16 waves/CU boundary)
// R8: last-block fused softmax w/ fences   -> 10x    (per-block device fence = L2 writeback storm)
// R5 (this) = local optimum: temporal, 2560 blocks, VGPR=64, 2-kernel tail.

// Kernel A: s1T[b][a][nt] = (sum_h neigh[b,nt,h]*node[b,t,h]*W[a,h] + b[a]) * rsqrt(nn[0])
// stored directly in the FINAL BA layout, plus neigh -> neigh_r passthrough copy.
__global__ __launch_bounds__(256) void ga_s1_copy(
    const float* __restrict__ node,     // [B][T][H]
    const float* __restrict__ neigh,    // [B][NT][H]
    const int*   __restrict__ nn,       // [B]
    const float* __restrict__ W,        // [HOPS][H]
    const float* __restrict__ bias,     // [HOPS]
    float* __restrict__ s1T,            // [B][HOPS][NT]  (aliases BA output slot)
    float* __restrict__ neigh_r)        // [B][NT][H]
{
    const int lane16 = threadIdx.x & 15;   // h-slice owner within a 16-lane group
    const int group  = threadIdx.x >> 4;   // 16 position-groups per block
    const int chunk  = blockIdx.x % CHUNKS;
    const int b      = blockIdx.x / CHUNKS;

    const float rscale = rsqrtf((float)nn[0]);

    // W fragment for this thread's fixed h-slice (h = lane16*8 .. +7)
    f32x4 w0[HOPS], w1[HOPS];
    #pragma unroll
    for (int a = 0; a < HOPS; ++a) {
        const f32x4* wp = reinterpret_cast<const f32x4*>(W + a * Hh + lane16 * 8);
        w0[a] = wp[0];
        w1[a] = wp[1];
    }
    const float bl = bias[lane16 >> 1];   // hop owned by this lane-pair after butterfly

    const int pos0 = chunk * POS_PER_BLOCK + group;       // pass p handles pos0 + 16p
    const size_t base = ((size_t)b * NT + pos0) * Hh + lane16 * 8;

    // 1) hoist all passes' neigh loads: 2*PPT dwordx4 in flight
    f32x4 nb[PPT][2];
    #pragma unroll
    for (int p = 0; p < PPT; ++p) {
        const f32x4* np = reinterpret_cast<const f32x4*>(neigh + base + (size_t)p * 16 * Hh);
        nb[p][0] = np[0];
        nb[p][1] = np[1];
    }
    // 2) fused passthrough copy (exact f32)
    #pragma unroll
    for (int p = 0; p < PPT; ++p) {
        f32x4* cp = reinterpret_cast<f32x4*>(neigh_r + base + (size_t)p * 16 * Hh);
        cp[0] = nb[p][0];
        cp[1] = nb[p][1];
    }

    // 3) compute + payload-split butterfly reduce (8 shuffles per pass)
    #pragma unroll
    for (int p = 0; p < PPT; ++p) {
        const int pos = pos0 + p * 16;
        const int t   = pos % Tt;
        const f32x4* dp = reinterpret_cast<const f32x4*>(node + ((size_t)b * Tt + t) * Hh + lane16 * 8);
        const f32x4 pr0 = nb[p][0] * dp[0];
        const f32x4 pr1 = nb[p][1] * dp[1];

        float acc[HOPS];
        #pragma unroll
        for (int a = 0; a < HOPS; ++a) {
            acc[a] = pr0[0] * w0[a][0] + pr0[1] * w0[a][1] + pr0[2] * w0[a][2] + pr0[3] * w0[a][3]
                   + pr1[0] * w1[a][0] + pr1[1] * w1[a][1] + pr1[2] * w1[a][2] + pr1[3] * w1[a][3];
        }

        // Level 1 (xor 8): keep own half of hop-set, exchange the other half.
        const bool h8 = (lane16 & 8) != 0;
        float r[4];
        #pragma unroll
        for (int k = 0; k < 4; ++k) {
            float send = h8 ? acc[k] : acc[k + 4];
            r[k] = (h8 ? acc[k + 4] : acc[k]) + __shfl_xor(send, 8, 64);
        }
        // Level 2 (xor 4)
        const bool h4 = (lane16 & 4) != 0;
        float s2[2];
        #pragma unroll
        for (int k = 0; k < 2; ++k) {
            float send = h4 ? r[k] : r[k + 2];
            s2[k] = (h4 ? r[k + 2] : r[k]) + __shfl_xor(send, 4, 64);
        }
        // Level 3 (xor 2)
        const bool h2 = (lane16 & 2) != 0;
        float send3 = h2 ? s2[0] : s2[1];
        float u = (h2 ? s2[1] : s2[0]) + __shfl_xor(send3, 2, 64);
        // Level 4 (xor 1): full sum; lane 2k (and 2k+1) now hold hop k's total
        u += __shfl_xor(u, 1, 64);

        if (!(lane16 & 1)) {
            const int k = lane16 >> 1;
            s1T[((size_t)b * HOPS + k) * NT + pos] = (u + bl) * rscale;
        }
    }
}

// Kernel D (fused B+C): one block per b. 1024 threads = 8 hop-rows x 128 threads.
// Register-resident softmax per row, P staged in padded LDS tile, BW summed in-block.
__global__ __launch_bounds__(1024) void ga_softmax_bw(float* __restrict__ out)
{
    float* BW = out;                       // [B][NT]
    float* BA = out + Bb * NT;             // [B][HOPS][NT] (holds s1T; rewritten in place)
    const int b  = blockIdx.x;
    const int tl = threadIdx.x & 127;      // position lane within the row
    const int r  = threadIdx.x >> 7;       // hop-row 0..7 (waves 2r, 2r+1)
    const int wave = threadIdx.x >> 6;
    const int lane = threadIdx.x & 63;

    float* row = BA + ((size_t)b * HOPS + r) * NT;

    // 13 strided values per thread (k==12 valid only for tl<64: 12*128+64=1600)
    float v[13];
    #pragma unroll
    for (int k = 0; k < 13; ++k) {
        const int nt = k * 128 + tl;
        v[k] = (nt < NT) ? row[nt] : -INFINITY;
    }

    __shared__ float redm[16], reds[16];
    __shared__ float sP[HOPS][NT + 4];     // stride 1604 (mod 32 = 4) -> conflict-free a-column reads

    // row max across 128 threads (2 waves)
    float m = v[0];
    #pragma unroll
    for (int k = 1; k < 13; ++k) m = fmaxf(m, v[k]);
    #pragma unroll
    for (int off = 32; off >= 1; off >>= 1) m = fmaxf(m, __shfl_xor(m, off, 64));
    if (lane == 0) redm[wave] = m;
    __syncthreads();
    m = fmaxf(redm[r * 2], redm[r * 2 + 1]);

    // exp + row sum
    float e[13];
    float s = 0.f;
    #pragma unroll
    for (int k = 0; k < 13; ++k) {
        const int nt = k * 128 + tl;
        e[k] = (nt < NT) ? __expf(v[k] - m) : 0.f;
        s += e[k];
    }
    #pragma unroll
    for (int off = 32; off >= 1; off >>= 1) s += __shfl_xor(s, off, 64);
    if (lane == 0) reds[wave] = s;
    __syncthreads();
    const float inv = 1.0f / (reds[r * 2] + reds[r * 2 + 1]);

    // write softmax row (coalesced 512B per k-slice) + stage P in LDS
    #pragma unroll
    for (int k = 0; k < 13; ++k) {
        const int nt = k * 128 + tl;
        if (nt < NT) {
            const float p = e[k] * inv;
            row[nt] = p;
            sP[r][nt] = p;
        }
    }
    __syncthreads();

    // BW[b][nt] = sum_a P[a][nt] from LDS
    for (int nt = threadIdx.x; nt < NT; nt += 1024) {
        float ssum = 0.f;
        #pragma unroll
        for (int a = 0; a < HOPS; ++a) ssum += sP[a][nt];
        BW[(size_t)b * NT + nt] = ssum;
    }
}

} // namespace

extern "C" void kernel_launch(void* const* d_in, const int* in_sizes, int n_in,
                              void* d_out, int out_size, void* d_ws, size_t ws_size,
                              hipStream_t stream) {
    const float* node  = (const float*)d_in[0];   // [128][50][128] f32
    const float* neigh = (const float*)d_in[1];   // [128][32][50][128] f32
    const int*   nn    = (const int*)d_in[2];     // [128] i32
    const float* W     = (const float*)d_in[3];   // [8][128] f32
    const float* bias  = (const float*)d_in[4];   // [8] f32

    float* out     = (float*)d_out;
    float* BA      = out + Bb * NT;            // after BW (204800)
    float* neigh_r = BA + Bb * HOPS * NT;      // after BA (1638400)

    ga_s1_copy<<<dim3(Bb * CHUNKS), dim3(256), 0, stream>>>(node, neigh, nn, W, bias, BA, neigh_r);
    ga_softmax_bw<<<dim3(Bb), dim3(1024), 0, stream>>>(out);
}